// Round 5
// baseline (57.663 us; speedup 1.0000x reference)
//
#include <hip/hip_runtime.h>
#include <hip/hip_bf16.h>

typedef __bf16 bf16x8 __attribute__((ext_vector_type(8)));
typedef float  f32x4  __attribute__((ext_vector_type(4)));

namespace {
constexpr int kB = 16;
constexpr int kT = 2048;
constexpr int kD = 128;
constexpr int RB = 64;       // rows per block; EVERY wave covers all 64 rows
constexpr int CT = 64;       // columns per tile; each wave owns a 16-col slice
constexpr int NT = kT / CT;  // 32 tiles
constexpr float TH_SIM  = 0.9f;
constexpr float TH_DIFF = 0.1f;
constexpr float BIGF    = 1e9f;
}

// ---------------------------------------------------------------- label scan
// One block per batch: stable-partition positions (fakes first) + fake count.
__global__ __launch_bounds__(256) void scan_kernel(const int* __restrict__ label,
                                                   int* __restrict__ perm,
                                                   int* __restrict__ cFarr) {
    const int b = blockIdx.x, tid = threadIdx.x;
    const int* lb = label + b * kT;
    int loc[8], cnt = 0;
    #pragma unroll
    for (int j = 0; j < 8; ++j) { loc[j] = (lb[tid * 8 + j] == 0); cnt += loc[j]; }
    __shared__ int s[256];
    s[tid] = cnt;
    __syncthreads();
    for (int off = 1; off < 256; off <<= 1) {
        const int v = (tid >= off) ? s[tid - off] : 0;
        __syncthreads();
        s[tid] += v;
        __syncthreads();
    }
    const int total = s[255];
    if (tid == 0) cFarr[b] = total;
    int run = s[tid] - cnt;
    #pragma unroll
    for (int j = 0; j < 8; ++j) {
        const int i = tid * 8 + j;
        perm[b * kT + i] = loc[j] ? run : (total + i - run);
        run += loc[j];
    }
}

// ---------------------------------------------------------------- normalize + scatter
__global__ __launch_bounds__(256) void nrm_kernel(const float* __restrict__ emb,
                                                  const int* __restrict__ perm,
                                                  __hip_bfloat16* __restrict__ out) {
    const int wave = threadIdx.x >> 6;
    const int lane = threadIdx.x & 63;
    const int row  = blockIdx.x * 4 + wave;
    const float2 v = *reinterpret_cast<const float2*>(emb + (size_t)row * kD + lane * 2);
    float ss = v.x * v.x + v.y * v.y;
    #pragma unroll
    for (int m = 1; m < 64; m <<= 1) ss += __shfl_xor(ss, m);
    const float inv = ss > 0.f ? rsqrtf(ss) : 0.f;
    const int b   = row >> 11;
    const int dst = perm[row];
    __hip_bfloat162 o;
    o.x = __float2bfloat16(v.x * inv);
    o.y = __float2bfloat16(v.y * inv);
    *reinterpret_cast<__hip_bfloat162*>(out + ((size_t)(b * kT + dst)) * kD + lane * 2) = o;
}

// ---------------------------------------------------------------- main
// No LDS in the K-loop: each wave owns a disjoint 16-col slice per tile, so
// B-fragments load straight from global (L2-resident) into registers.
// A-frags carry the row sign (real rows negated): per-value stats = one v_min.
// MODE 0: all cols fake; 1: all cols real; 2: mixed (boundary tile).
template <int MODE>
__device__ __forceinline__ void compute_vals(const bf16x8 (&bfrag)[4],
                                             const bf16x8 (&afrag)[4][4],
                                             float (&u1)[4][4], float (&u2)[4][4],
                                             bool cfake) {
    #pragma unroll
    for (int rg = 0; rg < 4; ++rg) {
        f32x4 acc = {0.f, 0.f, 0.f, 0.f};
        #pragma unroll
        for (int kk = 0; kk < 4; ++kk)
            acc = __builtin_amdgcn_mfma_f32_16x16x32_bf16(afrag[rg][kk], bfrag[kk], acc, 0, 0, 0);
        if (MODE == 0) {
            #pragma unroll
            for (int r = 0; r < 4; ++r) u1[rg][r] = fminf(u1[rg][r], acc[r]);
        } else if (MODE == 1) {
            #pragma unroll
            for (int r = 0; r < 4; ++r) u2[rg][r] = fminf(u2[rg][r], -acc[r]);
        } else {
            #pragma unroll
            for (int r = 0; r < 4; ++r) {
                u1[rg][r] = fminf(u1[rg][r], cfake ? acc[r] : BIGF);
                u2[rg][r] = fminf(u2[rg][r], cfake ? BIGF : -acc[r]);
            }
        }
    }
}

__global__ __launch_bounds__(256, 2) void crloss_main(const __hip_bfloat16* __restrict__ nrm,
                                                      const int* __restrict__ cFarr,
                                                      float* __restrict__ partials) {
    __shared__ float mrg[2][4][RB];   // cross-wave stat merge only (2 KiB)
    const int bid  = blockIdx.x;
    const int b    = bid >> 5;
    const int rb   = bid & 31;
    const int tid  = threadIdx.x;
    const int wave = tid >> 6;        // which 16-col slice of each tile
    const int lane = tid & 63;
    const int lo   = lane & 15;
    const int hi   = lane >> 4;

    const short* nb = reinterpret_cast<const short*>(nrm) + (size_t)b * kT * kD;
    const int cf   = cFarr[b];
    const int row0 = rb * RB;
    const int col  = wave * 16 + lo;  // column within tile owned by this lane

    // A fragments for ALL 64 rows: [row-group][k-block]; lane holds row rg*16+lo
    bf16x8 afrag[4][4];
    #pragma unroll
    for (int rg = 0; rg < 4; ++rg) {
        #pragma unroll
        for (int kk = 0; kk < 4; ++kk)
            afrag[rg][kk] = *reinterpret_cast<const bf16x8*>(
                nb + (size_t)(row0 + rg * 16 + lo) * kD + kk * 32 + hi * 8);
        if (row0 + rg * 16 + lo >= cf) {   // fold row sign: negate real rows
            unsigned* u = reinterpret_cast<unsigned*>(&afrag[rg][0]);
            #pragma unroll
            for (int q = 0; q < 16; ++q) u[q] ^= 0x80008000u;
        }
    }

    float u1[4][4], u2[4][4];
    #pragma unroll
    for (int rg = 0; rg < 4; ++rg)
        #pragma unroll
        for (int r = 0; r < 4; ++r) { u1[rg][r] = BIGF; u2[rg][r] = BIGF; }

    const short* bp = nb + (size_t)col * kD + hi * 8;  // per-lane B base
    auto loadB = [&](bf16x8 (&bf)[4], int ct) {
        const short* p = bp + (size_t)ct * (CT * kD);
        #pragma unroll
        for (int kk = 0; kk < 4; ++kk)
            bf[kk] = *reinterpret_cast<const bf16x8*>(p + kk * 32);
    };

    const int  ctF    = cf >> 6;
    const bool hasMix = (cf & 63) != 0;
    auto comp = [&](const bf16x8 (&bf)[4], int ct) {
        if (ct < ctF)
            compute_vals<0>(bf, afrag, u1, u2, false);
        else if (ct == ctF && hasMix)
            compute_vals<2>(bf, afrag, u1, u2, (ct * CT + col) < cf);
        else
            compute_vals<1>(bf, afrag, u1, u2, false);
    };

    // register double-buffered pipeline, all frag indices static (rule #20)
    bf16x8 bA[4], bB[4];
    loadB(bA, 0);
    loadB(bB, 1);
    for (int ct = 0; ct < NT; ct += 2) {
        comp(bA, ct);
        if (ct + 2 < NT) loadB(bA, ct + 2);
        comp(bB, ct + 1);
        if (ct + 3 < NT) loadB(bB, ct + 3);
    }

    // merge the 16 col-lanes (same hi => same rows)
    #pragma unroll
    for (int m = 1; m <= 8; m <<= 1) {
        #pragma unroll
        for (int rg = 0; rg < 4; ++rg)
            #pragma unroll
            for (int r = 0; r < 4; ++r) {
                u1[rg][r] = fminf(u1[rg][r], __shfl_xor(u1[rg][r], m));
                u2[rg][r] = fminf(u2[rg][r], __shfl_xor(u2[rg][r], m));
            }
    }

    // cross-wave merge via LDS: all waves covered the same 64 rows, diff cols
    if (lo == 0) {
        #pragma unroll
        for (int rg = 0; rg < 4; ++rg)
            #pragma unroll
            for (int r = 0; r < 4; ++r) {
                mrg[0][wave][rg * 16 + hi * 4 + r] = u1[rg][r];
                mrg[1][wave][rg * 16 + hi * 4 + r] = u2[rg][r];
            }
    }
    __syncthreads();
    if (tid < RB) {
        const int row = tid;
        float a1 = BIGF, a2 = BIGF;
        #pragma unroll
        for (int w = 0; w < 4; ++w) {
            a1 = fminf(a1, mrg[0][w][row]);
            a2 = fminf(a2, mrg[1][w][row]);
        }
        const bool f   = (row0 + row) < cf;
        const float mn = f ? a1 : a2;
        const float mx = f ? -a2 : -a1;
        const float l  = fmaxf(TH_SIM - mn, 0.f) + fmaxf(mx - TH_DIFF, 0.f);
        float sF = f ? l : 0.f;
        float sR = f ? 0.f : l;
        #pragma unroll
        for (int m = 1; m < 64; m <<= 1) {
            sF += __shfl_xor(sF, m);
            sR += __shfl_xor(sR, m);
        }
        if (tid == 0) {
            partials[bid * 2]     = sF;
            partials[bid * 2 + 1] = sR;
        }
    }
}

// ---------------------------------------------------------------- finalize
__global__ __launch_bounds__(512) void crloss_final(const float* __restrict__ partials,
                                                    const int* __restrict__ cFarr,
                                                    float* __restrict__ out) {
    const int t = threadIdx.x;
    float pf = partials[t * 2];
    float pr = partials[t * 2 + 1];
    #pragma unroll
    for (int m = 1; m <= 16; m <<= 1) {   // reduce 32 consecutive entries (one batch)
        pf += __shfl_xor(pf, m);
        pr += __shfl_xor(pr, m);
    }
    __shared__ float sF[16], sR[16];
    if ((t & 31) == 0) { sF[t >> 5] = pf; sR[t >> 5] = pr; }
    __syncthreads();
    if (t == 0) {
        float tot = 0.f;
        for (int b = 0; b < kB; ++b) {
            const int cf = cFarr[b], cr = kT - cf;
            if (cf > 0 && cr > 0)
                tot += sF[b] / (float)cf + sR[b] / (float)cr;
        }
        out[0] = tot / (float)kB;
    }
}

// ---------------------------------------------------------------- launch
extern "C" void kernel_launch(void* const* d_in, const int* in_sizes, int n_in,
                              void* d_out, int out_size, void* d_ws, size_t ws_size,
                              hipStream_t stream) {
    const float* emb   = (const float*)d_in[0];
    const int*   label = (const int*)d_in[1];
    float*       out   = (float*)d_out;

    char* ws = (char*)d_ws;
    __hip_bfloat16* nrm = (__hip_bfloat16*)ws;                       // 8 MiB
    int*   perm     = (int*)(ws + (size_t)kB * kT * kD * 2);         // 128 KiB
    int*   cFarr    = (int*)(ws + (size_t)kB * kT * kD * 2 + kB * kT * 4);
    float* partials = (float*)(ws + (size_t)kB * kT * kD * 2 + kB * kT * 4 + 64);

    scan_kernel<<<kB, 256, 0, stream>>>(label, perm, cFarr);
    nrm_kernel<<<kB * kT / 4, 256, 0, stream>>>(emb, perm, nrm);
    crloss_main<<<kB * (kT / RB), 256, 0, stream>>>(nrm, cFarr, partials);
    crloss_final<<<1, 512, 0, stream>>>(partials, cFarr, out);
}